// Round 14
// baseline (323.456 us; speedup 1.0000x reference)
//
#include <hip/hip_runtime.h>
#include <hip/hip_bf16.h>

// Problem constants (B,T,S,D = 32,1024,1024,512)
#define B_ 32
#define T_ 1024
#define S_ 1024
#define D_ 512
#define M_ (B_*T_)       // 32768 GEMM rows
#define N_ D_            // 512  GEMM cols
#define K_ (2*D_)        // 1024 GEMM reduction

typedef __attribute__((ext_vector_type(8))) short bf16x8;  // 8 bf16 = 4 VGPRs
typedef __attribute__((ext_vector_type(4))) float f32x4;

__device__ inline unsigned short f2bf(float x) {
    union { float f; unsigned u; } v; v.f = x;
    unsigned r = v.u + 0x7FFFu + ((v.u >> 16) & 1u);   // RNE
    return (unsigned short)(r >> 16);
}

// pack 2 f32 -> 2 bf16 (RNE), packed in 32 bits
__device__ inline unsigned cvt2bf(float lo, float hi) {
#if __has_builtin(__builtin_amdgcn_cvt_pk_bf16_f32)
    typedef __attribute__((ext_vector_type(2))) __bf16 bf2;
    union { bf2 v; unsigned u; } r;
    r.v = __builtin_amdgcn_cvt_pk_bf16_f32(lo, hi);
    return r.u;
#else
    return (unsigned)f2bf(lo) | ((unsigned)f2bf(hi) << 16);
#endif
}

// fast tanh: 1 - 2/(e^{2x}+1) via hw exp2 + rcp. rel err ~1e-7, exact sat at +-1.
__device__ inline float fast_tanh(float x) {
#if __has_builtin(__builtin_amdgcn_exp2f) && __has_builtin(__builtin_amdgcn_rcpf)
    const float e = __builtin_amdgcn_exp2f(x * 2.885390082f);   // e^{2x}
    const float r = __builtin_amdgcn_rcpf(e + 1.0f);
    return 1.0f - 2.0f * r;
#else
    return tanhf(x);
#endif
}

// ---------------------------------------------------------------------------
// Kernel 1 (merged): blocks [0,32) = alignment scan -> jbuf (wave 0 only);
// blocks [32, 288) = W f32 -> bf16 pack. One launch instead of two.
// ---------------------------------------------------------------------------
__global__ __launch_bounds__(256)
void align_pack(const int* __restrict__ iv, int* __restrict__ jbuf,
                const float* __restrict__ W, unsigned short* __restrict__ Wbf) {
    if (blockIdx.x < 32) {
        if (threadIdx.x >= 64) return;         // wave 0 only
        const int b = blockIdx.x;
        const int lane = threadIdx.x;          // 16 tokens per lane
        const int* row = iv + b * T_;
        int f[16];
        int local = 0;
        const int t0 = lane * 16;
        #pragma unroll
        for (int q = 0; q < 16; ++q) {
            const int t = t0 + q;
            const int tok = row[t];
            const int fl = (t > 0 && (tok == 1 || tok == 2)) ? 1 : 0;
            f[q] = fl;
            local += fl;
        }
        int incl = local;
        #pragma unroll
        for (int off = 1; off < 64; off <<= 1) {
            const int up = __shfl_up(incl, off, 64);
            if (lane >= off) incl += up;
        }
        int run = incl - local;                // exclusive prefix at lane start
        #pragma unroll
        for (int q = 0; q < 16; ++q) {
            const int t = t0 + q;
            run += f[q];
            int j;
            if (t == 0) {
                j = 0;                         // attn[b,0,0] = 1 always
            } else {
                j = t - run - 1;
                if (j < 0) j += S_;            // torch negative-index wrap
            }
            jbuf[b * T_ + t] = j;
        }
        return;
    }
    // ---- pack W: 256 blocks x 256 threads, 8 bf16 per thread
    const int idx = (blockIdx.x - 32) * 256 + threadIdx.x;   // < N_*K_/8
    const f32x4 a = ((const f32x4*)W)[idx * 2];
    const f32x4 c = ((const f32x4*)W)[idx * 2 + 1];
    union { bf16x8 v; unsigned u[4]; } pk;
    pk.u[0] = cvt2bf(a[0], a[1]); pk.u[1] = cvt2bf(a[2], a[3]);
    pk.u[2] = cvt2bf(c[0], c[1]); pk.u[3] = cvt2bf(c[2], c[3]);
    *(bf16x8*)(Wbf + (size_t)idx * 8) = pk.v;
}

// ---------------------------------------------------------------------------
// Kernel 2: GEMM 256x256, grid = 256 blocks (1/CU, ONE generation).
//
// R19 = R18 + (a) Bs DOUBLE-BUFFER: DMA_B(i+1 -> Bs[p^1]) moves into the
// fly-under-MFMA batch, drained at barrier-2 with full MFMA cover (B's
// previous position at the iter top had only the ~100cy cvt as cover ->
// 300-600cy exposed L2 latency per iter at barrier-1). Barrier-1 now waits
// only on LDS writes. Hazard: Bs[p^1] last read by MFMA(i-1), separated by
// two barriers. Zero register cost (DMA has no VGPR result); LDS 96 KB
// (still 1 block/CU -> free). (b) sched_barrier(0) pins the fly-under batch
// (attn NT + LOAD_A + DMA_B) BEFORE the MFMA phase so the scheduler can't
// sink the issues and strip their cover.
//
// K-loop per iter (p = i&1):
//   STAGE_A(i): cvt fa -> As               (fa drained last iter)
//   sync1  [lgkm only in steady state]
//   attn rows(NT) + LOAD_A(i+1) + DMA_B(i+1 -> Bs[p^1])   [pinned]
//   MFMA on As, Bs[p]                      (all three fly under it)
//   sync2  [drains A(i+1), B(i+1), attn with MFMA cover]
// ---------------------------------------------------------------------------
#define BM 256
#define BN 256
#define BK 64
#define NIT (K_ / BK)                    // 16
#define KMAX (K_ - BK)                   // 960
#define NGEMM ((M_ / BM) * (N_ / BN))    // 128*2 = 256

__global__ __launch_bounds__(512, 2)
void gemm_attn(const unsigned short* __restrict__ Wbf,
               const float* __restrict__ bias,
               float* __restrict__ out,
               float* __restrict__ attn,
               const float* __restrict__ ctx,
               const float* __restrict__ outp,
               const int* __restrict__ jbuf) {
    const int bx = blockIdx.x;
    const int tid = threadIdx.x;

    __shared__ unsigned short As[BM * BK];        // 32 KB
    __shared__ unsigned short Bs[2][BN * BK];     // 2 x 32 KB (96 KB total)

    // ---------------- GEMM tile 256x256 ----------------
    const int lane = tid & 63;
    const int wave = tid >> 6;                   // 0..7
    const int wm = wave >> 1, wn = wave & 1;     // 4x2 waves -> 64x128 each
    const int l16 = lane & 15, quad = lane >> 4;

    // sibling-adjacent same-XCD map: bn-pair of each bm spaced 8 apart.
    const int xcd = bx & 7;
    const int bn  = (bx >> 3) & 1;               // 2 n-tiles of 256
    const int bm  = ((bx >> 4) << 3) | xcd;      // 128 m-tiles of 256
    const int mBase = bm * BM;
    const int nBase = bn * BN;

    // A staging: chunk c = it*512+tid, row = it*64 + (tid>>3), g = tid&7.
    const int g    = tid & 7;
    const int rsub = tid >> 3;                   // 0..63
    const int sw   = g ^ (rsub & 7);             // swizzle, it-invariant (64%8==0)
    const float* actx[4];
    const float* aout[4];
    const unsigned short* bSrc[4];
    #pragma unroll
    for (int it = 0; it < 4; ++it) {
        const int r = it * 64 + rsub;
        const int m = mBase + r;
        const int jm = jbuf[m];
        actx[it] = ctx + ((size_t)((m >> 10) * S_ + jm)) * D_ + g * 8;
        aout[it] = outp + (size_t)m * D_ - D_ + g * 8;      // add ko>=512
        // B: row&7 == rsub&7 -> source granule == sw (pre-swizzled, linear dest)
        bSrc[it] = Wbf + (size_t)(nBase + r) * K_ + sw * 8;
    }

    // attn quota: 128 rows starting here; 8 per K-iter, row = base + it*8 + wave
    const int aBase = mBase + bn * 128;

    f32x4 acc[4][8] = {};
    f32x4 fa[4][2];

#define LOAD_A(KO) do {                                                        \
    const int _koa = (KO);                                                     \
    _Pragma("unroll")                                                          \
    for (int _it = 0; _it < 4; ++_it) {                                        \
        const float* _src = (_koa < D_) ? (actx[_it] + _koa) : (aout[_it] + _koa); \
        fa[_it][0] = ((const f32x4*)_src)[0];                                  \
        fa[_it][1] = ((const f32x4*)_src)[1];                                  \
    }                                                                          \
} while (0)

#define DMA_B(P, KO) do {                                                      \
    const int _kob = (KO);                                                     \
    _Pragma("unroll")                                                          \
    for (int _it = 0; _it < 4; ++_it) {                                        \
        __builtin_amdgcn_global_load_lds(                                      \
            (const __attribute__((address_space(1))) void*)(bSrc[_it] + _kob), \
            (__attribute__((address_space(3))) void*)(&Bs[P][(_it * 512 + tid) * 8]), \
            16, 0, 0);                                                         \
    }                                                                          \
} while (0)

    // prologue: A(0) + B(0) in flight; B(0) waits at sync1(0) (one-time).
    LOAD_A(0);
    DMA_B(0, 0);

    #pragma unroll 1
    for (int i = 0; i < NIT; ++i) {
        const int ko = i * BK;
        const int p  = i & 1;
        const int kon = (ko + BK > KMAX) ? KMAX : ko + BK;   // clamped tail

        // ---- 1. cvt + swizzled ds_write_b128 (fa loads drained or waited here)
        #pragma unroll
        for (int it = 0; it < 4; ++it) {
            union { bf16x8 v; unsigned u[4]; } pk;
            pk.u[0] = cvt2bf(fa[it][0][0], fa[it][0][1]);
            pk.u[1] = cvt2bf(fa[it][0][2], fa[it][0][3]);
            pk.u[2] = cvt2bf(fa[it][1][0], fa[it][1][1]);
            pk.u[3] = cvt2bf(fa[it][1][2], fa[it][1][3]);
            *(bf16x8*)&As[(it * 512 + rsub * 8 + sw) * 8] = pk.v;
        }
        __syncthreads();       // sync1: ds_writes visible; B(i) done (MFMA(i-1) cover)

        // ---- 2. fly-under batch (pinned before MFMA): attn + A(i+1) + B(i+1)
        {
            const int arow = aBase + i * 8 + wave;     // wave-uniform row
            const int jv = jbuf[arow];                 // scalar broadcast
            f32x4* abase = (f32x4*)(attn + (size_t)arow * S_);
            #pragma unroll
            for (int s = 0; s < 4; ++s) {
                const int col = lane + 64 * s;
                f32x4 v = {0.f, 0.f, 0.f, 0.f};
                if ((jv >> 2) == col) v[jv & 3] = 1.0f;
                __builtin_nontemporal_store(v, abase + col);
            }
        }
        LOAD_A(kon);                                   // A(i+1)
        DMA_B(p ^ 1, kon);                             // B(i+1) -> other buffer
        __builtin_amdgcn_sched_barrier(0);             // pin issues before MFMA

        // ---- 3. MFMA phase: 2 K-steps of 32; 32 MFMA each (4mt x 8nt)
        #pragma unroll
        for (int ks = 0; ks < 2; ++ks) {
            bf16x8 af[4], bfr[8];
            const int q = ks * 4 + quad;
            #pragma unroll
            for (int mt = 0; mt < 4; ++mt) {
                const int r = wm * 64 + mt * 16 + l16;
                af[mt] = *(const bf16x8*)&As[(r * 8 + (q ^ (r & 7))) * 8];
            }
            #pragma unroll
            for (int nt = 0; nt < 8; ++nt) {
                const int rb = wn * 128 + nt * 16 + l16;
                bfr[nt] = *(const bf16x8*)&Bs[p][(rb * 8 + (q ^ (rb & 7))) * 8];
            }
            #pragma unroll
            for (int mt = 0; mt < 4; ++mt)
                #pragma unroll
                for (int nt = 0; nt < 8; ++nt)
                    acc[mt][nt] = __builtin_amdgcn_mfma_f32_16x16x32_bf16(
                        af[mt], bfr[nt], acc[mt][nt], 0, 0, 0);
        }
        __syncthreads();       // sync2: drain A(i+1)+B(i+1)+attn (MFMA cover)
    }

#undef LOAD_A
#undef DMA_B

    // ---- epilogue: fast_tanh(acc + bias), fp32 NT store
    #pragma unroll
    for (int nt = 0; nt < 8; ++nt) {
        const int n = nBase + wn * 128 + nt * 16 + l16;
        const float bv = bias[n];
        #pragma unroll
        for (int mt = 0; mt < 4; ++mt) {
            #pragma unroll
            for (int r = 0; r < 4; ++r) {
                const int m = mBase + wm * 64 + mt * 16 + quad * 4 + r;
                const float val = fast_tanh(acc[mt][nt][r] + bv);
                __builtin_nontemporal_store(val, &out[(size_t)m * N_ + n]);
            }
        }
    }
}

// ---------------------------------------------------------------------------
extern "C" void kernel_launch(void* const* d_in, const int* in_sizes, int n_in,
                              void* d_out, int out_size, void* d_ws, size_t ws_size,
                              hipStream_t stream) {
    const int*   iv   = (const int*)d_in[0];    // input_var [B,T]
    const float* outp = (const float*)d_in[1];  // output   [B,T,D]
    const float* ctx  = (const float*)d_in[2];  // context  [B,S,D]
    // d_in[3] = di (unused by reference body)
    const float* W    = (const float*)d_in[4];  // [D, 2D]
    const float* bias = (const float*)d_in[5];  // [D]

    float* out  = (float*)d_out;                       // [B,T,D]
    float* attn = out + (size_t)M_ * N_;               // [B,T,S]

    // workspace layout: j[M_] int32 | Wbf[N_*K_] bf16   (~1.1 MB total)
    int* jbuf = (int*)d_ws;
    unsigned short* Wbf = (unsigned short*)((char*)d_ws + (size_t)M_ * 4);

    align_pack<<<32 + (N_ * K_ / 8) / 256, 256, 0, stream>>>(iv, jbuf, W, Wbf);
    gemm_attn<<<NGEMM, 512, 0, stream>>>(Wbf, bias, out, attn, ctx, outp, jbuf);
}